// Round 7
// baseline (429.284 us; speedup 1.0000x reference)
//
#include <hip/hip_runtime.h>
#include <hip/hip_bf16.h>
#include <math.h>

typedef __attribute__((ext_vector_type(8))) short bf16x8;
typedef __attribute__((ext_vector_type(4))) float f32x4;

__device__ inline unsigned short f2bf(float f) {
    return __builtin_bit_cast(unsigned short, __float2bfloat16(f));
}
__device__ inline float bf2f(unsigned short u) {
    return __bfloat162float(__builtin_bit_cast(__hip_bfloat16, u));
}
__device__ inline bf16x8 cvt8(float4 a, float4 b) {
    bf16x8 r;
    r[0]=(short)f2bf(a.x); r[1]=(short)f2bf(a.y); r[2]=(short)f2bf(a.z); r[3]=(short)f2bf(a.w);
    r[4]=(short)f2bf(b.x); r[5]=(short)f2bf(b.y); r[6]=(short)f2bf(b.z); r[7]=(short)f2bf(b.w);
    return r;
}
__device__ inline void split8(float4 a, float4 b, bf16x8& hi, bf16x8& lo) {
    float f[8] = {a.x,a.y,a.z,a.w,b.x,b.y,b.z,b.w};
    #pragma unroll
    for (int i = 0; i < 8; ++i) {
        unsigned short h = f2bf(f[i]);
        hi[i] = (short)h;
        lo[i] = (short)f2bf(f[i] - bf2f(h));
    }
}

// LDS map (f32 idx units; total 6403 fl = 25612 B -> 6 blocks/CU), per slice:
//  xv   f32 [25][65]     @0     whole slice (LN src, xvT src, residual)
//  ynh  u16 [25][64]swz  @1628  LN..qk
//  ynl  u16 [25][64]swz  @2428
//  A_bf u16 [80][40]     @1628  softmax..z   (overlays yn; rows 75+ garbage, discarded)
//  zA   u16 [25][200]    @1628  zwrite..conv (overlays A_bf+xvT after drain barrier)
//  qkb  f32 [25][52]     @3228  qk..dots
//  xvT  u16 [64][40]     @3228  phase4..z    (overlays qkb after dots)
//  Abuf f32 [75][25]     @4528  dots..softmax
//  res  f32 [64][25]     @4528  conv..store  (overlays Abuf)
#define LDS_FLOATS 6403

__global__ __launch_bounds__(256, 6)
void agcn_fused_kernel(const float* __restrict__ x,
                       const float* __restrict__ PA,
                       const float* __restrict__ ln_g, const float* __restrict__ ln_b,
                       const float* __restrict__ Wqk, const float* __restrict__ bqk,
                       const float* __restrict__ conv_w, const float* __restrict__ conv_b,
                       const float* __restrict__ bn_g, const float* __restrict__ bn_b,
                       const float* __restrict__ bn_m, const float* __restrict__ bn_v,
                       float* __restrict__ out)
{
    __shared__ float lds[LDS_FLOATS];
    float* xv = lds;                                      // [25][65]
    unsigned short* ynh  = (unsigned short*)(lds + 1628);
    unsigned short* ynl  = (unsigned short*)(lds + 2428);
    unsigned short* A_bf = (unsigned short*)(lds + 1628); // [80][40]
    unsigned short* zA   = (unsigned short*)(lds + 1628); // [25][200]
    float* qkb  = lds + 3228;                             // [25][52]
    unsigned short* xvT  = (unsigned short*)(lds + 3228); // [64][40]
    float* Abuf = lds + 4528;                             // [75][25]
    float* res  = lds + 4528;                             // [64][25]

    const int bid = blockIdx.x;
    const int n = bid >> 5;                 // 128 n's
    const int tb = (bid & 31) << 2;         // 32 groups of 4 t's
    const int tid = threadIdx.x;
    const int lane = tid & 63, w = tid >> 6;
    const int g = lane >> 4, l15 = lane & 15;
    const int o = 16 * w + l15;

    // ============ prologue (once per 4 slices) ============
    float4 cw_f[12];
    #pragma unroll
    for (int kt = 0; kt < 6; ++kt) {
        const float* wp = &conv_w[(kt >> 1) * 4096 + o * 64 + (kt & 1) * 32 + 8 * g];
        cw_f[2*kt]   = *(const float4*)wp;
        cw_f[2*kt+1] = *(const float4*)(wp + 4);
    }
    float4 wq_f[4];
    float bq = 0.f;
    if (w < 3) {
        const int j = 16 * w + l15;
        #pragma unroll
        for (int ks = 0; ks < 2; ++ks) {
            const float* wp = &Wqk[j * 64 + ks * 32 + 8 * g];
            wq_f[2*ks]   = *(const float4*)wp;
            wq_f[2*ks+1] = *(const float4*)(wp + 4);
        }
        bq = bqk[j];
    }
    // hoisted LN + epilogue constants
    const float lg = ln_g[lane], lb = ln_b[lane];
    const float sc_e = bn_g[o] * rsqrtf(bn_v[o] + 1e-5f);
    const float bi_e = (conv_b[o] + conv_b[64 + o] + conv_b[128 + o]) * sc_e
                       + bn_b[o] - bn_m[o] * sc_e;

    // slice 0 x -> xv
    {
        const float* xb = x + (size_t)n * 204800 + tb * 25;
        for (int idx = tid; idx < 1600; idx += 256) {
            int c = idx / 25, v = idx - c * 25;
            xv[v * 65 + c] = xb[c * 3200 + v];
        }
    }

    bf16x8 cw[6];
    #pragma unroll
    for (int kt = 0; kt < 6; ++kt) cw[kt] = cvt8(cw_f[2*kt], cw_f[2*kt+1]);
    bf16x8 wqh[2], wql[2];
    if (w < 3) {
        #pragma unroll
        for (int ks = 0; ks < 2; ++ks) split8(wq_f[2*ks], wq_f[2*ks+1], wqh[ks], wql[ks]);
    }
    __syncthreads();

    float pf[7];
    #pragma unroll 1
    for (int s = 0; s < 4; ++s) {
        const int t = tb + s;

        // A. prefetch next slice's x into regs (latency hidden under this slice)
        if (s < 3) {
            const float* xb = x + (size_t)n * 204800 + (t + 1) * 25;
            #pragma unroll
            for (int k = 0; k < 7; ++k) {
                int idx = tid + (k << 8);
                if (idx < 1600) {
                    int c = idx / 25, v = idx - c * 25;
                    pf[k] = xb[c * 3200 + v];
                }
            }
        }

        // B. LayerNorm -> yn hi/lo (bf16, swizzled)
        for (int v = w; v < 25; v += 4) {
            float val = xv[v * 65 + lane];
            float sm = val;
            for (int off = 32; off; off >>= 1) sm += __shfl_xor(sm, off);
            float mu = sm * (1.0f / 64.0f);
            float d = val - mu;
            float s2 = d * d;
            for (int off = 32; off; off >>= 1) s2 += __shfl_xor(s2, off);
            float rstd = rsqrtf(s2 * (1.0f / 64.0f) + 1e-5f);
            float y = d * rstd * lg + lb;
            unsigned short hh = f2bf(y);
            unsigned short ll = f2bf(y - bf2f(hh));
            int idx = (v * 64 + lane) ^ ((v & 7) << 3);
            ynh[idx] = hh;
            ynl[idx] = ll;
        }
        __syncthreads();

        // C. qk MFMA (waves 0-2) -> qkb f32
        if (w < 3) {
            const int j = 16 * w + l15;
            #pragma unroll
            for (int mt = 0; mt < 2; ++mt) {
                f32x4 acc = {bq, bq, bq, bq};
                #pragma unroll
                for (int ks = 0; ks < 2; ++ks) {
                    int row = 16 * mt + l15;
                    int idx = (row * 64 + ks * 32 + 8 * g) ^ ((row & 7) << 3);
                    bf16x8 ah = *(bf16x8*)&ynh[idx];
                    bf16x8 al = *(bf16x8*)&ynl[idx];
                    acc = __builtin_amdgcn_mfma_f32_16x16x32_bf16(al, wqh[ks], acc, 0, 0, 0);
                    acc = __builtin_amdgcn_mfma_f32_16x16x32_bf16(ah, wql[ks], acc, 0, 0, 0);
                    acc = __builtin_amdgcn_mfma_f32_16x16x32_bf16(ah, wqh[ks], acc, 0, 0, 0);
                }
                #pragma unroll
                for (int reg = 0; reg < 4; ++reg) {
                    int v = 16 * mt + 4 * g + reg;
                    if (v < 25) qkb[v * 52 + j] = acc[reg];
                }
            }
        }
        __syncthreads();

        // D. dots (fp32 VALU, all threads) -> Abuf
        for (int idx = tid; idx < 1875; idx += 256) {
            int h = idx / 625, r = idx - h * 625;
            int i = r / 25, j = r - i * 25;
            const float4* q = (const float4*)&qkb[i * 52 + h * 8];
            const float4* k = (const float4*)&qkb[j * 52 + 24 + h * 8];
            float4 q0 = q[0], q1 = q[1], k0 = k[0], k1 = k[1];
            float d = q0.x*k0.x + q0.y*k0.y + q0.z*k0.z + q0.w*k0.w
                    + q1.x*k1.x + q1.y*k1.y + q1.z*k1.z + q1.w*k1.w;
            Abuf[idx] = d * 0.35355339059327373f;
        }
        __syncthreads();

        // E. softmax*PA (tid<75) -> A_bf ; xvT build (tid>=96, qkb now dead)
        if (tid < 75) {
            int h = tid / 25, i = tid - h * 25;
            const float* row = &Abuf[h * 625 + i * 25];
            const float* pa = &PA[h * 625 + i * 25];
            float m = row[0];
            #pragma unroll
            for (int j = 1; j < 25; ++j) m = fmaxf(m, row[j]);
            float e[25];
            float sm = 0.f;
            #pragma unroll
            for (int j = 0; j < 25; ++j) { e[j] = __expf(row[j] - m); sm += e[j]; }
            float inv = 1.0f / sm;
            unsigned short* ar = &A_bf[(h * 25 + i) * 40];
            #pragma unroll
            for (int j = 0; j < 25; ++j) ar[j] = f2bf(e[j] * inv * pa[j]);
            #pragma unroll
            for (int j = 25; j < 32; ++j) ar[j] = 0;
        } else if (tid >= 96) {
            for (int idx = tid - 96; idx < 2560; idx += 160) {
                int c = idx / 40, jj = idx - c * 40;
                xvT[idx] = f2bf(jj < 25 ? xv[jj * 65 + c] : 0.f);
            }
        }
        __syncthreads();

        // F. z MFMA -> regs (zA write deferred past drain barrier)
        f32x4 zacc[5];
        {
            bf16x8 bfrag = *(bf16x8*)&xvT[(16 * w + l15) * 40 + 8 * g];
            #pragma unroll
            for (int mt = 0; mt < 5; ++mt) {
                bf16x8 afrag = *(bf16x8*)&A_bf[(16 * mt + l15) * 40 + 8 * g];
                f32x4 a = {0.f, 0.f, 0.f, 0.f};
                zacc[mt] = __builtin_amdgcn_mfma_f32_16x16x32_bf16(afrag, bfrag, a, 0, 0, 0);
            }
        }
        __syncthreads();   // frag reads drained; A_bf/xvT dead

        // G. zA write
        #pragma unroll
        for (int mt = 0; mt < 5; ++mt) {
            #pragma unroll
            for (int reg = 0; reg < 4; ++reg) {
                int r = 16 * mt + 4 * g + reg;
                if (r < 75) {
                    int h = r / 25, i = r - h * 25;
                    zA[i * 200 + h * 64 + 16 * w + l15] = f2bf(zacc[mt][reg]);
                }
            }
        }
        __syncthreads();

        // H. conv MFMA + BN + residual + ReLU -> res
        {
            const int r1 = (16 + l15 < 25) ? (16 + l15) : 0;
            f32x4 acc0 = {0.f, 0.f, 0.f, 0.f}, acc1 = {0.f, 0.f, 0.f, 0.f};
            #pragma unroll
            for (int kt = 0; kt < 6; ++kt) {
                bf16x8 a0 = *(bf16x8*)&zA[l15 * 200 + 32 * kt + 8 * g];
                bf16x8 a1 = *(bf16x8*)&zA[r1 * 200 + 32 * kt + 8 * g];
                acc0 = __builtin_amdgcn_mfma_f32_16x16x32_bf16(a0, cw[kt], acc0, 0, 0, 0);
                acc1 = __builtin_amdgcn_mfma_f32_16x16x32_bf16(a1, cw[kt], acc1, 0, 0, 0);
            }
            #pragma unroll
            for (int reg = 0; reg < 4; ++reg) {
                int v = 4 * g + reg;
                float val = acc0[reg] * sc_e + bi_e + xv[v * 65 + o];
                res[o * 25 + v] = fmaxf(val, 0.f);
            }
            #pragma unroll
            for (int reg = 0; reg < 4; ++reg) {
                int v = 16 + 4 * g + reg;
                if (v < 25) {
                    float val = acc1[reg] * sc_e + bi_e + xv[v * 65 + o];
                    res[o * 25 + v] = fmaxf(val, 0.f);
                }
            }
        }
        __syncthreads();

        // I. coalesced store; commit prefetched x -> xv for next slice
        {
            float* ob = out + (size_t)n * 204800 + t * 25;
            for (int idx = tid; idx < 1600; idx += 256) {
                int c = idx / 25, v = idx - c * 25;
                ob[c * 3200 + v] = res[idx];
            }
            if (s < 3) {
                #pragma unroll
                for (int k = 0; k < 7; ++k) {
                    int idx = tid + (k << 8);
                    if (idx < 1600) {
                        int c = idx / 25, v = idx - c * 25;
                        xv[v * 65 + c] = pf[k];
                    }
                }
            }
        }
        __syncthreads();
    }
}

extern "C" void kernel_launch(void* const* d_in, const int* in_sizes, int n_in,
                              void* d_out, int out_size, void* d_ws, size_t ws_size,
                              hipStream_t stream) {
    const float* x      = (const float*)d_in[0];
    const float* PA     = (const float*)d_in[1];
    const float* ln_g   = (const float*)d_in[2];
    const float* ln_b   = (const float*)d_in[3];
    const float* Wqk    = (const float*)d_in[4];
    const float* bqk    = (const float*)d_in[5];
    const float* conv_w = (const float*)d_in[6];
    const float* conv_b = (const float*)d_in[7];
    const float* bn_g   = (const float*)d_in[8];
    const float* bn_b   = (const float*)d_in[9];
    const float* bn_m   = (const float*)d_in[10];
    const float* bn_v   = (const float*)d_in[11];
    float* outp = (float*)d_out;

    agcn_fused_kernel<<<dim3(4096), dim3(256), 0, stream>>>(
        x, PA, ln_g, ln_b, Wqk, bqk, conv_w, conv_b,
        bn_g, bn_b, bn_m, bn_v, outp);
}

// Round 8
// 423.870 us; speedup vs baseline: 1.0128x; 1.0128x over previous
//
#include <hip/hip_runtime.h>
#include <hip/hip_bf16.h>
#include <math.h>

typedef __attribute__((ext_vector_type(8))) short bf16x8;
typedef __attribute__((ext_vector_type(4))) float f32x4;

__device__ inline unsigned short f2bf(float f) {
    return __builtin_bit_cast(unsigned short, __float2bfloat16(f));
}
__device__ inline float bf2f(unsigned short u) {
    return __bfloat162float(__builtin_bit_cast(__hip_bfloat16, u));
}
__device__ inline bf16x8 cvt8(float4 a, float4 b) {
    bf16x8 r;
    r[0]=(short)f2bf(a.x); r[1]=(short)f2bf(a.y); r[2]=(short)f2bf(a.z); r[3]=(short)f2bf(a.w);
    r[4]=(short)f2bf(b.x); r[5]=(short)f2bf(b.y); r[6]=(short)f2bf(b.z); r[7]=(short)f2bf(b.w);
    return r;
}
__device__ inline void split8(float4 a, float4 b, bf16x8& hi, bf16x8& lo) {
    float f[8] = {a.x,a.y,a.z,a.w,b.x,b.y,b.z,b.w};
    #pragma unroll
    for (int i = 0; i < 8; ++i) {
        unsigned short h = f2bf(f[i]);
        hi[i] = (short)h;
        lo[i] = (short)f2bf(f[i] - bf2f(h));
    }
}

// LDS map (f32 idx units; total 6403 fl = 25612 B -> 6 blocks/CU), per slice:
//  xv   f32 [25][65]     @0     whole slice (LN src, xvT src, residual)
//  ynh  u16 [25][64]swz  @1628  LN..qk
//  ynl  u16 [25][64]swz  @2428
//  A_bf u16 [80][40]     @1628  softmax..z   (overlays yn; rows 75+ garbage, discarded)
//  zA   u16 [25][200]    @1628  zwrite..conv (overlays A_bf+xvT after drain barrier)
//  qkb  f32 [25][52]     @3228  qk..dots
//  xvT  u16 [64][40]     @3228  phase4..z    (overlays qkb after dots)
//  Abuf f32 [75][25]     @4528  dots..softmax
//  res  f32 [64][25]     @4528  conv..store  (overlays Abuf)
#define LDS_FLOATS 6403

__global__ __launch_bounds__(256, 6)
void agcn_fused_kernel(const float* __restrict__ x,
                       const float* __restrict__ PA,
                       const float* __restrict__ ln_g, const float* __restrict__ ln_b,
                       const float* __restrict__ Wqk, const float* __restrict__ bqk,
                       const float* __restrict__ conv_w, const float* __restrict__ conv_b,
                       const float* __restrict__ bn_g, const float* __restrict__ bn_b,
                       const float* __restrict__ bn_m, const float* __restrict__ bn_v,
                       float* __restrict__ out)
{
    __shared__ float lds[LDS_FLOATS];
    float* xv = lds;                                      // [25][65]
    unsigned short* ynh  = (unsigned short*)(lds + 1628);
    unsigned short* ynl  = (unsigned short*)(lds + 2428);
    unsigned short* A_bf = (unsigned short*)(lds + 1628); // [80][40]
    unsigned short* zA   = (unsigned short*)(lds + 1628); // [25][200]
    float* qkb  = lds + 3228;                             // [25][52]
    unsigned short* xvT  = (unsigned short*)(lds + 3228); // [64][40]
    float* Abuf = lds + 4528;                             // [75][25]
    float* res  = lds + 4528;                             // [64][25]

    const int bid = blockIdx.x;
    const int n = bid >> 5;                 // 128 n's
    const int k32 = bid & 31;               // slice s handles t = k32 + 32*s
    const int tid = threadIdx.x;
    const int lane = tid & 63, w = tid >> 6;
    const int g = lane >> 4, l15 = lane & 15;
    const int o = 16 * w + l15;

    // ============ prologue (once per 4 slices) ============
    float4 cw_f[12];
    #pragma unroll
    for (int kt = 0; kt < 6; ++kt) {
        const float* wp = &conv_w[(kt >> 1) * 4096 + o * 64 + (kt & 1) * 32 + 8 * g];
        cw_f[2*kt]   = *(const float4*)wp;
        cw_f[2*kt+1] = *(const float4*)(wp + 4);
    }
    float4 wq_f[4];
    float bq = 0.f;
    if (w < 3) {
        const int j = 16 * w + l15;
        #pragma unroll
        for (int ks = 0; ks < 2; ++ks) {
            const float* wp = &Wqk[j * 64 + ks * 32 + 8 * g];
            wq_f[2*ks]   = *(const float4*)wp;
            wq_f[2*ks+1] = *(const float4*)(wp + 4);
        }
        bq = bqk[j];
    }
    // hoisted LN + epilogue constants
    const float lg = ln_g[lane], lb = ln_b[lane];
    const float sc_e = bn_g[o] * rsqrtf(bn_v[o] + 1e-5f);
    const float bi_e = (conv_b[o] + conv_b[64 + o] + conv_b[128 + o]) * sc_e
                       + bn_b[o] - bn_m[o] * sc_e;

    // slice 0 x -> xv
    {
        const float* xb = x + (size_t)n * 204800 + k32 * 25;
        for (int idx = tid; idx < 1600; idx += 256) {
            int c = idx / 25, v = idx - c * 25;
            xv[v * 65 + c] = xb[c * 3200 + v];
        }
    }

    bf16x8 cw[6];
    #pragma unroll
    for (int kt = 0; kt < 6; ++kt) cw[kt] = cvt8(cw_f[2*kt], cw_f[2*kt+1]);
    bf16x8 wqh[2], wql[2];
    if (w < 3) {
        #pragma unroll
        for (int ks = 0; ks < 2; ++ks) split8(wq_f[2*ks], wq_f[2*ks+1], wqh[ks], wql[ks]);
    }
    __syncthreads();

    float pf[7];
    #pragma unroll 1
    for (int s = 0; s < 4; ++s) {
        const int t = k32 + (s << 5);

        // A. prefetch next slice's x (t+32) into regs
        if (s < 3) {
            const float* xb = x + (size_t)n * 204800 + (t + 32) * 25;
            #pragma unroll
            for (int kk = 0; kk < 7; ++kk) {
                int idx = tid + (kk << 8);
                if (idx < 1600) {
                    int c = idx / 25, v = idx - c * 25;
                    pf[kk] = xb[c * 3200 + v];
                }
            }
        }

        // B. LayerNorm -> yn hi/lo (bf16, swizzled)
        for (int v = w; v < 25; v += 4) {
            float val = xv[v * 65 + lane];
            float sm = val;
            for (int off = 32; off; off >>= 1) sm += __shfl_xor(sm, off);
            float mu = sm * (1.0f / 64.0f);
            float d = val - mu;
            float s2 = d * d;
            for (int off = 32; off; off >>= 1) s2 += __shfl_xor(s2, off);
            float rstd = rsqrtf(s2 * (1.0f / 64.0f) + 1e-5f);
            float y = d * rstd * lg + lb;
            unsigned short hh = f2bf(y);
            unsigned short ll = f2bf(y - bf2f(hh));
            int idx = (v * 64 + lane) ^ ((v & 7) << 3);
            ynh[idx] = hh;
            ynl[idx] = ll;
        }
        __syncthreads();

        // C. qk MFMA (waves 0-2) -> qkb f32
        if (w < 3) {
            const int j = 16 * w + l15;
            #pragma unroll
            for (int mt = 0; mt < 2; ++mt) {
                f32x4 acc = {bq, bq, bq, bq};
                #pragma unroll
                for (int ks = 0; ks < 2; ++ks) {
                    int row = 16 * mt + l15;
                    int idx = (row * 64 + ks * 32 + 8 * g) ^ ((row & 7) << 3);
                    bf16x8 ah = *(bf16x8*)&ynh[idx];
                    bf16x8 al = *(bf16x8*)&ynl[idx];
                    acc = __builtin_amdgcn_mfma_f32_16x16x32_bf16(al, wqh[ks], acc, 0, 0, 0);
                    acc = __builtin_amdgcn_mfma_f32_16x16x32_bf16(ah, wql[ks], acc, 0, 0, 0);
                    acc = __builtin_amdgcn_mfma_f32_16x16x32_bf16(ah, wqh[ks], acc, 0, 0, 0);
                }
                #pragma unroll
                for (int reg = 0; reg < 4; ++reg) {
                    int v = 16 * mt + 4 * g + reg;
                    if (v < 25) qkb[v * 52 + j] = acc[reg];
                }
            }
        }
        __syncthreads();

        // D. dots (fp32 VALU, all threads) -> Abuf
        for (int idx = tid; idx < 1875; idx += 256) {
            int h = idx / 625, r = idx - h * 625;
            int i = r / 25, j = r - i * 25;
            const float4* q = (const float4*)&qkb[i * 52 + h * 8];
            const float4* kp = (const float4*)&qkb[j * 52 + 24 + h * 8];
            float4 q0 = q[0], q1 = q[1], k0 = kp[0], k1 = kp[1];
            float d = q0.x*k0.x + q0.y*k0.y + q0.z*k0.z + q0.w*k0.w
                    + q1.x*k1.x + q1.y*k1.y + q1.z*k1.z + q1.w*k1.w;
            Abuf[idx] = d * 0.35355339059327373f;
        }
        __syncthreads();

        // E. softmax*PA (tid<75) -> A_bf ; xvT build (tid>=96, qkb now dead)
        if (tid < 75) {
            int h = tid / 25, i = tid - h * 25;
            const float* row = &Abuf[h * 625 + i * 25];
            const float* pa = &PA[h * 625 + i * 25];
            float m = row[0];
            #pragma unroll
            for (int j = 1; j < 25; ++j) m = fmaxf(m, row[j]);
            float e[25];
            float sm = 0.f;
            #pragma unroll
            for (int j = 0; j < 25; ++j) { e[j] = __expf(row[j] - m); sm += e[j]; }
            float inv = 1.0f / sm;
            unsigned short* ar = &A_bf[(h * 25 + i) * 40];
            #pragma unroll
            for (int j = 0; j < 25; ++j) ar[j] = f2bf(e[j] * inv * pa[j]);
            #pragma unroll
            for (int j = 25; j < 32; ++j) ar[j] = 0;
        } else if (tid >= 96) {
            for (int idx = tid - 96; idx < 2560; idx += 160) {
                int c = idx / 40, jj = idx - c * 40;
                xvT[idx] = f2bf(jj < 25 ? xv[jj * 65 + c] : 0.f);
            }
        }
        __syncthreads();

        // F. z MFMA -> regs (zA write deferred past drain barrier)
        f32x4 zacc[5];
        {
            bf16x8 bfrag = *(bf16x8*)&xvT[(16 * w + l15) * 40 + 8 * g];
            #pragma unroll
            for (int mt = 0; mt < 5; ++mt) {
                bf16x8 afrag = *(bf16x8*)&A_bf[(16 * mt + l15) * 40 + 8 * g];
                f32x4 a = {0.f, 0.f, 0.f, 0.f};
                zacc[mt] = __builtin_amdgcn_mfma_f32_16x16x32_bf16(afrag, bfrag, a, 0, 0, 0);
            }
        }
        __syncthreads();   // frag reads drained; A_bf/xvT dead

        // G. zA write
        #pragma unroll
        for (int mt = 0; mt < 5; ++mt) {
            #pragma unroll
            for (int reg = 0; reg < 4; ++reg) {
                int r = 16 * mt + 4 * g + reg;
                if (r < 75) {
                    int h = r / 25, i = r - h * 25;
                    zA[i * 200 + h * 64 + 16 * w + l15] = f2bf(zacc[mt][reg]);
                }
            }
        }
        __syncthreads();

        // H. conv MFMA + BN + residual + ReLU -> res
        {
            const int r1 = (16 + l15 < 25) ? (16 + l15) : 0;
            f32x4 acc0 = {0.f, 0.f, 0.f, 0.f}, acc1 = {0.f, 0.f, 0.f, 0.f};
            #pragma unroll
            for (int kt = 0; kt < 6; ++kt) {
                bf16x8 a0 = *(bf16x8*)&zA[l15 * 200 + 32 * kt + 8 * g];
                bf16x8 a1 = *(bf16x8*)&zA[r1 * 200 + 32 * kt + 8 * g];
                acc0 = __builtin_amdgcn_mfma_f32_16x16x32_bf16(a0, cw[kt], acc0, 0, 0, 0);
                acc1 = __builtin_amdgcn_mfma_f32_16x16x32_bf16(a1, cw[kt], acc1, 0, 0, 0);
            }
            #pragma unroll
            for (int reg = 0; reg < 4; ++reg) {
                int v = 4 * g + reg;
                float val = acc0[reg] * sc_e + bi_e + xv[v * 65 + o];
                res[o * 25 + v] = fmaxf(val, 0.f);
            }
            #pragma unroll
            for (int reg = 0; reg < 4; ++reg) {
                int v = 16 + 4 * g + reg;
                if (v < 25) {
                    float val = acc1[reg] * sc_e + bi_e + xv[v * 65 + o];
                    res[o * 25 + v] = fmaxf(val, 0.f);
                }
            }
        }
        __syncthreads();

        // I. coalesced store; commit prefetched x -> xv for next slice
        {
            float* ob = out + (size_t)n * 204800 + t * 25;
            for (int idx = tid; idx < 1600; idx += 256) {
                int c = idx / 25, v = idx - c * 25;
                ob[c * 3200 + v] = res[idx];
            }
            if (s < 3) {
                #pragma unroll
                for (int kk = 0; kk < 7; ++kk) {
                    int idx = tid + (kk << 8);
                    if (idx < 1600) {
                        int c = idx / 25, v = idx - c * 25;
                        xv[v * 65 + c] = pf[kk];
                    }
                }
            }
        }
        __syncthreads();
    }
}

extern "C" void kernel_launch(void* const* d_in, const int* in_sizes, int n_in,
                              void* d_out, int out_size, void* d_ws, size_t ws_size,
                              hipStream_t stream) {
    const float* x      = (const float*)d_in[0];
    const float* PA     = (const float*)d_in[1];
    const float* ln_g   = (const float*)d_in[2];
    const float* ln_b   = (const float*)d_in[3];
    const float* Wqk    = (const float*)d_in[4];
    const float* bqk    = (const float*)d_in[5];
    const float* conv_w = (const float*)d_in[6];
    const float* conv_b = (const float*)d_in[7];
    const float* bn_g   = (const float*)d_in[8];
    const float* bn_b   = (const float*)d_in[9];
    const float* bn_m   = (const float*)d_in[10];
    const float* bn_v   = (const float*)d_in[11];
    float* outp = (float*)d_out;

    agcn_fused_kernel<<<dim3(4096), dim3(256), 0, stream>>>(
        x, PA, ln_g, ln_b, Wqk, bqk, conv_w, conv_b,
        bn_g, bn_b, bn_m, bn_v, outp);
}